// Round 5
// baseline (299.767 us; speedup 1.0000x reference)
//
#include <hip/hip_runtime.h>
#include <stdint.h>

// triplet_loss_cl: loss = mean_i(-log(softmax(q G^T)[i,i] + 1e-5)), N=8192, D=256.
// Flash-style, never materialize logits. q pre-scaled by log2(e); MFMA C-input
// initialized to -KOFF so logits exit MFMA already offset; epilogue is bare exp2.
// Offset cancels exactly in p = exp2(l_ii)/sum exp2(l).
//
// Round 11: rounds 9/10 proved k_main (~12us) is no longer dominant; budget
// analysis shows ~32us of dispatch-boundary overhead across the 4-dispatch
// chain (fill->cvt->main->fin). Fuse cvt+main+fin into ONE kernel with device
// grid barriers: grid 256 x 512 (<=1 block/CU always fits -> all blocks
// co-resident by construction, spin barriers deadlock-free). Barriers are
// monotonic generation counters in __device__ globals (module-load zeroed,
// never reset -> no init kernel, graph-replay safe). Phase B = round-10 inner
// loop verbatim, 2 col-splits per block (8 contiguous panels, afrag reused).
// A/B use the identical chunk packing, so any k-permutation in the HW fragment
// map applies to both operands and cancels in the dot product.

#define LOG2E 1.44269504f
#define KOFF  92.3324826f          // 64 * log2(e); cancels exactly in p = e_ii/Z

typedef __attribute__((ext_vector_type(4))) float f32x4;
typedef __attribute__((ext_vector_type(4))) int   i32x4;
typedef __attribute__((ext_vector_type(8))) int   i32x8;

typedef __attribute__((address_space(1))) const uint32_t gu32;
typedef __attribute__((address_space(3))) uint32_t lu32;

__device__ unsigned g_bar[4];      // .bss, zeroed at module load; monotonic

static __device__ __forceinline__ i32x8 cat8(i32x4 lo, i32x4 hi) {
    i32x8 r;
    r[0] = lo[0]; r[1] = lo[1]; r[2] = lo[2]; r[3] = lo[3];
    r[4] = hi[0]; r[5] = hi[1]; r[6] = hi[2]; r[7] = hi[3];
    return r;
}

// Grid barrier over exactly 256 blocks, generation-free (monotonic counter).
// All 256 blocks are co-resident (grid <= #CUs, block fits 1/CU) -> no deadlock.
static __device__ __forceinline__ void grid_barrier(unsigned* bar) {
    __threadfence();                               // release phase writes (agent)
    __syncthreads();
    if (threadIdx.x == 0) {
        unsigned my = __hip_atomic_fetch_add(bar, 1u, __ATOMIC_ACQ_REL,
                                             __HIP_MEMORY_SCOPE_AGENT);
        unsigned tgt = (my | 255u) + 1u;           // next multiple of 256
        while (__hip_atomic_load(bar, __ATOMIC_ACQUIRE,
                                 __HIP_MEMORY_SCOPE_AGENT) < tgt)
            __builtin_amdgcn_s_sleep(4);
    }
    __syncthreads();
    __threadfence();                               // acquire others' writes
}

// ---- fused kernel: cvt -> barrier -> main -> barrier -> fin ----
// Phase A: fp32 [8192][256] -> fp8 e4m3 K=128 fragment panels (qb, gb).
//   Panel = 64 rows x 256 k = 16 KB, 8 tiles (kb in 2, cf in 4) of 2 KB;
//   tile rows cf*16+l15, k = kb*128+quad*32..+32, stored [h in 2][lane][16B].
// Phase B: 16 row-tiles (BM=512) x 16 col-split-pairs. 8 waves x 64 rows.
//   Per block: 8 contiguous 64-col panels (2 col-splits), double-buffered LDS,
//   per panel 4 cf x (4 ds_read_b128 + 16 MX-MFMA) + exp2 epilogue.
//   Unit e8m0 scales (0x7F = 2^0) keep the math exact fp8.
// Phase C: per-row loss over 32 rows/block + last-block final reduce.
__global__ __launch_bounds__(512, 2) void k_all(const float* __restrict__ q,
                                                const float* __restrict__ g,
                                                char* __restrict__ qb,
                                                char* __restrict__ gb,
                                                float* __restrict__ zpart,
                                                float* __restrict__ diag,
                                                float* __restrict__ partial,
                                                float* __restrict__ out) {
    __shared__ char lds[2][16384];                 // double-buffered 64-col B tile
    __shared__ float red[8];
    __shared__ int lastflag;
    const int tid = threadIdx.x;

    // ---------------- phase A: convert ----------------
    {
        int gid = blockIdx.x * 512 + tid;          // [0, 131072)
#pragma unroll
        for (int i = 0; i < 4; ++i) {
            int o = i * 131072 + gid;              // i<2: q, i>=2: g (uniform)
            const float* src = q; char* dst = qb; float sc = LOG2E;
            if (o >= 262144) { o -= 262144; src = g; dst = gb; sc = 1.0f; }
            int row = o >> 5, slot = o & 31;
            const float4* sp = (const float4*)(src + row * 256 + slot * 8);
            float4 a = sp[0], b = sp[1];
            uint32_t w0 = __builtin_amdgcn_cvt_pk_fp8_f32(a.x*sc, a.y*sc, 0, false);
            w0 = __builtin_amdgcn_cvt_pk_fp8_f32(a.z*sc, a.w*sc, w0, true);
            uint32_t w1 = __builtin_amdgcn_cvt_pk_fp8_f32(b.x*sc, b.y*sc, 0, false);
            w1 = __builtin_amdgcn_cvt_pk_fp8_f32(b.z*sc, b.w*sc, w1, true);
            int p = row >> 6, cfr = (row >> 4) & 3, l15r = row & 15;
            int kb = slot >> 4;                    // which 128-k block
            int gi = slot & 15;                    // 8-byte granule within block
            int qd = gi >> 2;                      // lane quad (k = qd*32..+32)
            int j  = gi & 3;                       // byte granule within lane's 32B
            uint2 wv; wv.x = w0; wv.y = w1;
            *(uint2*)(dst + (size_t)p * 16384 + ((kb * 4 + cfr) << 11)
                      + ((j >> 1) << 10) + (qd * 16 + l15r) * 16 + (j & 1) * 8) = wv;
        }
    }

    grid_barrier(&g_bar[0]);

    // ---------------- phase B: main ----------------
    const int wave = tid >> 6;                     // 0..7
    const int lane = tid & 63;
    const int l15  = lane & 15;
    const int quad = lane >> 4;
    const int t    = blockIdx.x >> 4;              // row-tile (512 rows), 0..15
    const int cs0  = (blockIdx.x & 15) * 2;        // even col-split of the pair
    const int p64  = t * 8 + wave;                 // global 64-row panel index
    const int rowbase = p64 * 64;

    // A fragments: wave owns q-panel p64; rowgroup rg = tile cf. 64 VGPRs.
    i32x8 afrag[4][2];
    {
        const char* qp = qb + (size_t)p64 * 16384 + lane * 16;
#pragma unroll
        for (int rg = 0; rg < 4; ++rg)
#pragma unroll
            for (int kb = 0; kb < 2; ++kb) {
                const char* tp = qp + ((kb * 4 + rg) << 11);
                afrag[rg][kb] = cat8(*(const i32x4*)tp, *(const i32x4*)(tp + 1024));
            }
    }

    float zacc[4][4];
#pragma unroll
    for (int rg = 0; rg < 4; ++rg)
#pragma unroll
        for (int r = 0; r < 4; ++r) zacc[rg][r] = 0.f;

    // stage(jj, buf): 16 KB DMA, 8 waves x 2 x 1KB (linear; dest = uniform+lane*16)
    const char* gbase = gb + (size_t)(cs0 * 4) * 16384;   // 8 contiguous panels
#define STAGE(JJ, BUF)                                                        \
    {                                                                         \
        const char* gp = gbase + (size_t)(JJ) * 16384;                        \
        _Pragma("unroll")                                                     \
        for (int i = 0; i < 2; ++i) {                                         \
            int c = wave * 2 + i;                                             \
            __builtin_amdgcn_global_load_lds(                                 \
                (gu32*)(gp + (c << 10) + (lane << 4)),                        \
                (lu32*)(&lds[BUF][0] + (c << 10)), 16, 0, 0);                 \
        }                                                                     \
    }

    STAGE(0, 0);
    __syncthreads();                               // implicit vmcnt(0) drain
    int cur = 0;

    for (int jj = 0; jj < 8; ++jj) {               // 2 col-splits x 4 tiles
        if (jj < 7) STAGE(jj + 1, cur ^ 1);        // prefetch next tile

        const bool dg = (cs0 * 4 + jj == p64);     // tile holds our diagonal
        const char* lbase = &lds[cur][0] + lane * 16;
#pragma unroll 1                                   // runtime cf: caps B in flight
        for (int cf = 0; cf < 4; ++cf) {
            f32x4 acc[4];
#pragma unroll
            for (int rg = 0; rg < 4; ++rg)
                acc[rg] = (f32x4){-KOFF, -KOFF, -KOFF, -KOFF};
#pragma unroll
            for (int kb = 0; kb < 2; ++kb) {
                const char* bp = lbase + (cf << 11) + (kb << 13);
                i32x8 b = cat8(*(const i32x4*)bp, *(const i32x4*)(bp + 1024));
#pragma unroll
                for (int rg = 0; rg < 4; ++rg)
                    acc[rg] = __builtin_amdgcn_mfma_scale_f32_16x16x128_f8f6f4(
                        afrag[rg][kb], b, acc[rg],
                        0, 0,                       // cbsz/blgp: fp8 e4m3 / fp8 e4m3
                        0, 0x7f7f7f7f,              // scale A: e8m0 127 -> x1
                        0, 0x7f7f7f7f);             // scale B: e8m0 127 -> x1
            }
            // C/D layout: col=lane&15, row=quad*4+reg (shape-determined, m127/m128)
#pragma unroll
            for (int rg = 0; rg < 4; ++rg)
#pragma unroll
                for (int r = 0; r < 4; ++r)
                    zacc[rg][r] += __builtin_amdgcn_exp2f(acc[rg][r]);
            if (dg) {                              // diag: rg==cf, l15 == quad*4+r
#pragma unroll
                for (int rg = 0; rg < 4; ++rg)
                    if (rg == cf) {
#pragma unroll
                        for (int r = 0; r < 4; ++r)
                            if (quad * 4 + r == l15)
                                diag[rowbase + cf * 16 + l15] = acc[rg][r];
                    }
            }
        }

        if (jj == 3 || jj == 7) {                  // finished a col-split
            // fold the 16 column-lane-classes (lanes in bits 0..3 share a row)
#pragma unroll
            for (int d = 1; d < 16; d <<= 1)
#pragma unroll
                for (int rg = 0; rg < 4; ++rg)
#pragma unroll
                    for (int r = 0; r < 4; ++r)
                        zacc[rg][r] += __shfl_xor(zacc[rg][r], d, 64);
            if (l15 == 0) {
                int cs = cs0 + (jj >> 2);
#pragma unroll
                for (int rg = 0; rg < 4; ++rg)
#pragma unroll
                    for (int r = 0; r < 4; ++r)
                        zpart[(rowbase + rg * 16 + quad * 4 + r) * 32 + cs]
                            = zacc[rg][r];
            }
#pragma unroll
            for (int rg = 0; rg < 4; ++rg)
#pragma unroll
                for (int r = 0; r < 4; ++r) zacc[rg][r] = 0.f;
        }

        if (jj < 7) {
            __syncthreads();                       // drains this iter's STAGE
            cur ^= 1;
        }
    }
#undef STAGE

    grid_barrier(&g_bar[1]);

    // ---------------- phase C: per-row loss + final reduce ----------------
    {
        int row = blockIdx.x * 32 + (tid >> 4);    // 32 rows/block, 16 thr/row
        int cp  = tid & 15;
        float2 zz = *(const float2*)(zpart + row * 32 + cp * 2);
        float Zp = zz.x + zz.y;
#pragma unroll
        for (int d = 1; d < 16; d <<= 1) Zp += __shfl_xor(Zp, d, 64);
        float v = 0.f;
        if ((lane & 15) == 0) {                    // diag already has -KOFF folded
            float p = __builtin_amdgcn_exp2f(diag[row]) / Zp;
            v = -logf(p + 1e-5f);
        }
#pragma unroll
        for (int d = 16; d < 64; d <<= 1) v += __shfl_xor(v, d, 64);
        if (lane == 0) red[wave] = v;
        __syncthreads();
        if (tid == 0) {
            float bsum = ((red[0] + red[1]) + (red[2] + red[3]))
                       + ((red[4] + red[5]) + (red[6] + red[7]));
            __hip_atomic_store(&partial[blockIdx.x], bsum,
                               __ATOMIC_RELAXED, __HIP_MEMORY_SCOPE_AGENT);
            __threadfence();                       // release our partial
            unsigned my = __hip_atomic_fetch_add(&g_bar[2], 1u, __ATOMIC_ACQ_REL,
                                                 __HIP_MEMORY_SCOPE_AGENT);
            lastflag = ((my & 255u) == 255u);
        }
        __syncthreads();
        if (lastflag) {                            // we are the last block
            __threadfence();                       // acquire others' partials
            float v2 = 0.f;
            if (tid < 256)
                v2 = __hip_atomic_load(&partial[tid],
                                       __ATOMIC_RELAXED, __HIP_MEMORY_SCOPE_AGENT);
#pragma unroll
            for (int d = 1; d < 64; d <<= 1) v2 += __shfl_xor(v2, d, 64);
            if (tid < 256 && lane == 0) red[tid >> 6] = v2;
            __syncthreads();
            if (tid == 0)
                out[0] = ((red[0] + red[1]) + (red[2] + red[3])) * (1.f / 8192.f);
        }
    }
}

extern "C" void kernel_launch(void* const* d_in, const int* in_sizes, int n_in,
                              void* d_out, int out_size, void* d_ws, size_t ws_size,
                              hipStream_t stream) {
    const float* q = (const float*)d_in[0];
    const float* g = (const float*)d_in[1];
    char* ws = (char*)d_ws;
    char*  qb     = ws;                                        // 2 MiB fp8 panels
    char*  gb     = ws + (2u << 20);                           // 2 MiB fp8 panels
    float* diag   = (float*)(ws + (4u << 20));                 // 32 KiB
    float* zpart  = (float*)(ws + (4u << 20) + (32u << 10));   // 1 MiB
    float* partial= (float*)(ws + (4u << 20) + (1056u << 10)); // 1 KiB
    k_all<<<256, 512, 0, stream>>>(q, g, qb, gb, zpart, diag, partial,
                                   (float*)d_out);
    (void)in_sizes; (void)n_in; (void)out_size; (void)ws_size;
}

// Round 6
// 158.426 us; speedup vs baseline: 1.8922x; 1.8922x over previous
//
#include <hip/hip_runtime.h>
#include <stdint.h>

// triplet_loss_cl: loss = mean_i(-log(softmax(q G^T)[i,i] + 1e-5)), N=8192, D=256.
// Flash-style, never materialize logits. q pre-scaled by log2(e); MFMA C-input
// initialized to -KOFF so logits exit MFMA already offset; epilogue is bare exp2.
// Offset cancels exactly in p = exp2(l_ii)/sum exp2(l).
//
// Round 12: round-11's fused single-dispatch (spin grid barriers) burned ~230us
// in the barriers (phases ran at full speed per PMC) -> REVERTED to the round-10
// split structure (93.4us best). This round's single change: kill the k_fin
// dispatch. k_main blocks atomicAdd per-row Z partials into Zrow[] (zeroed by
// k_cvt), and the LAST k_main block to finish (monotonic device counter, no
// spinning anywhere) computes the final loss. Release/acquire chains through
// the ACQ_REL fetch_add; data read with one fence + relaxed agent loads.
// 8 waves x 64 rows (BM=512, grid 512, 2 blocks/CU): LDS traffic 256MB, MFMA
// floor 7.4us. Spill guards: launch_bounds(512,2), cf loop not unrolled.
// A/B use the identical chunk packing, so any k-permutation in the HW fragment
// map applies to both operands and cancels in the dot product.

#define LOG2E 1.44269504f
#define KOFF  92.3324826f          // 64 * log2(e); cancels exactly in p = e_ii/Z

typedef __attribute__((ext_vector_type(4))) float f32x4;
typedef __attribute__((ext_vector_type(4))) int   i32x4;
typedef __attribute__((ext_vector_type(8))) int   i32x8;

typedef __attribute__((address_space(1))) const uint32_t gu32;
typedef __attribute__((address_space(3))) uint32_t lu32;

__device__ unsigned g_ctr;         // .bss, zeroed at module load; monotonic

static __device__ __forceinline__ i32x8 cat8(i32x4 lo, i32x4 hi) {
    i32x8 r;
    r[0] = lo[0]; r[1] = lo[1]; r[2] = lo[2]; r[3] = lo[3];
    r[4] = hi[0]; r[5] = hi[1]; r[6] = hi[2]; r[7] = hi[3];
    return r;
}

// ---- kernel 0: fp32 row-major [8192][256] -> fp8 e4m3 K=128 fragment layout ----
// Panel = 64 rows x 256 k = 16 KB, split into 8 tiles (kb in 2, cf in 4) of 2 KB.
// Tile holds rows cf*16+l15, k = kb*128 + quad*32 .. +32 per lane (l=quad*16+l15),
// stored as [h in 2][lane][16B] so fragment loads are linear b128 pairs.
// Thread o -> row = o>>5 (coalesced reads), slot = o&31 (8 k-values each).
// Blocks 0..31 also zero the Zrow accumulator (stream-ordered before k_main).
__global__ __launch_bounds__(256) void k_cvt(const float* __restrict__ q,
                                             const float* __restrict__ g,
                                             char* __restrict__ qb,
                                             char* __restrict__ gb,
                                             float* __restrict__ Zrow) {
    if (blockIdx.x < 32) Zrow[blockIdx.x * 256 + threadIdx.x] = 0.f;
    int o = blockIdx.x * 256 + threadIdx.x;        // grid 2048: q then g
    const float* src = q;
    char* dst = qb;
    float sc = LOG2E;
    if (o >= 262144) { o -= 262144; src = g; dst = gb; sc = 1.0f; }
    int row = o >> 5, slot = o & 31;
    const float4* sp = (const float4*)(src + row * 256 + slot * 8);
    float4 a = sp[0], b = sp[1];
    uint32_t w0 = __builtin_amdgcn_cvt_pk_fp8_f32(a.x * sc, a.y * sc, 0, false);
    w0 = __builtin_amdgcn_cvt_pk_fp8_f32(a.z * sc, a.w * sc, w0, true);
    uint32_t w1 = __builtin_amdgcn_cvt_pk_fp8_f32(b.x * sc, b.y * sc, 0, false);
    w1 = __builtin_amdgcn_cvt_pk_fp8_f32(b.z * sc, b.w * sc, w1, true);
    int p = row >> 6, cf = (row >> 4) & 3, l15 = row & 15;
    int kb = slot >> 4;                            // which 128-k block
    int gi = slot & 15;                            // 8-byte granule within block
    int quad = gi >> 2;                            // lane quad (k = quad*32..+32)
    int j = gi & 3;                                // byte granule within lane's 32B
    uint2 wv; wv.x = w0; wv.y = w1;
    *(uint2*)(dst + (size_t)p * 16384 + ((kb * 4 + cf) << 11)
              + ((j >> 1) << 10) + (quad * 16 + l15) * 16 + (j & 1) * 8) = wv;
}

// ---- kernel 1: per-row Z (atomic) + diagonal + last-block loss finale ----
// grid 512 = 16 row-tiles (BM=512) x 32 col-splits (256 cols). 8 waves x 64 rows.
// Double-buffered B tiles: per jt {stage jt+1 -> buf^1 | 4 cf x (4 ds_read_b128 +
// 16 MX-MFMA) on buf | one barrier}. Unit e8m0 scales (0x7F = 2^0) = exact fp8.
// Epilogue: atomicAdd Z partials into Zrow; 512th block to arrive (monotonic
// counter, NO spinning) computes the final mean loss.
__global__ __launch_bounds__(512, 2) void k_main(const char* __restrict__ qb,
                                                 const char* __restrict__ gb,
                                                 float* __restrict__ Zrow,
                                                 float* __restrict__ diag,
                                                 float* __restrict__ out) {
    __shared__ char lds[2][16384];                 // double-buffered 64-col B tile
    __shared__ float red[8];
    __shared__ int lastflag;
    const int tid  = threadIdx.x;
    const int wave = tid >> 6;                     // 0..7
    const int lane = tid & 63;
    const int l15  = lane & 15;
    const int quad = lane >> 4;
    const int t    = blockIdx.x >> 5;              // row-tile (512 rows), 0..15
    const int cs   = blockIdx.x & 31;              // col-split (256 cols)
    const int p64  = t * 8 + wave;                 // global 64-row panel index
    const int rowbase = p64 * 64;

    // A fragments: wave owns q-panel p64; rowgroup rg = tile cf. 64 VGPRs.
    i32x8 afrag[4][2];
    {
        const char* qp = qb + (size_t)p64 * 16384 + lane * 16;
#pragma unroll
        for (int rg = 0; rg < 4; ++rg)
#pragma unroll
            for (int kb = 0; kb < 2; ++kb) {
                const char* tp = qp + ((kb * 4 + rg) << 11);
                afrag[rg][kb] = cat8(*(const i32x4*)tp, *(const i32x4*)(tp + 1024));
            }
    }

    float zacc[4][4];
#pragma unroll
    for (int rg = 0; rg < 4; ++rg)
#pragma unroll
        for (int r = 0; r < 4; ++r) zacc[rg][r] = 0.f;

    // stage(jt, buf): 16 KB DMA, 8 waves x 2 x 1KB (linear; dest = uniform+lane*16)
    const char* gbase = gb + (size_t)(cs * 4) * 16384;
#define STAGE(JT, BUF)                                                        \
    {                                                                         \
        const char* gp = gbase + (size_t)(JT) * 16384;                        \
        _Pragma("unroll")                                                     \
        for (int i = 0; i < 2; ++i) {                                         \
            int c = wave * 2 + i;                                             \
            __builtin_amdgcn_global_load_lds(                                 \
                (gu32*)(gp + (c << 10) + (lane << 4)),                        \
                (lu32*)(&lds[BUF][0] + (c << 10)), 16, 0, 0);                 \
        }                                                                     \
    }

    STAGE(0, 0);
    __syncthreads();                               // implicit vmcnt(0) drain
    int cur = 0;

    for (int jt = 0; jt < 4; ++jt) {
        if (jt < 3) STAGE(jt + 1, cur ^ 1);        // prefetch next tile

        const bool dg = (cs * 4 + jt == p64);      // tile holds our diagonal
        const char* lbase = &lds[cur][0] + lane * 16;
#pragma unroll 1                                   // runtime cf: caps B in flight
        for (int cf = 0; cf < 4; ++cf) {
            f32x4 acc[4];
#pragma unroll
            for (int rg = 0; rg < 4; ++rg)
                acc[rg] = (f32x4){-KOFF, -KOFF, -KOFF, -KOFF};
#pragma unroll
            for (int kb = 0; kb < 2; ++kb) {
                const char* bp = lbase + (cf << 11) + (kb << 13);
                i32x8 b = cat8(*(const i32x4*)bp, *(const i32x4*)(bp + 1024));
#pragma unroll
                for (int rg = 0; rg < 4; ++rg)
                    acc[rg] = __builtin_amdgcn_mfma_scale_f32_16x16x128_f8f6f4(
                        afrag[rg][kb], b, acc[rg],
                        0, 0,                       // cbsz/blgp: fp8 e4m3 / fp8 e4m3
                        0, 0x7f7f7f7f,              // scale A: e8m0 127 -> x1
                        0, 0x7f7f7f7f);             // scale B: e8m0 127 -> x1
            }
            // C/D layout: col=lane&15, row=quad*4+reg (shape-determined, m127/m128)
#pragma unroll
            for (int rg = 0; rg < 4; ++rg)
#pragma unroll
                for (int r = 0; r < 4; ++r)
                    zacc[rg][r] += __builtin_amdgcn_exp2f(acc[rg][r]);
            if (dg) {                              // diag: rg==cf, l15 == quad*4+r
#pragma unroll
                for (int rg = 0; rg < 4; ++rg)
                    if (rg == cf) {
#pragma unroll
                        for (int r = 0; r < 4; ++r)
                            if (quad * 4 + r == l15)
                                diag[rowbase + cf * 16 + l15] = acc[rg][r];
                    }
            }
        }
        if (jt < 3) {
            __syncthreads();                       // drains this iter's STAGE
            cur ^= 1;
        }
    }
#undef STAGE

    // fold the 16 column-lane-classes (lanes differing in bits 0..3 share a row)
#pragma unroll
    for (int d = 1; d < 16; d <<= 1)
#pragma unroll
        for (int rg = 0; rg < 4; ++rg)
#pragma unroll
            for (int r = 0; r < 4; ++r)
                zacc[rg][r] += __shfl_xor(zacc[rg][r], d, 64);

    if (l15 == 0) {                                // 32 adds/row total, low contention
#pragma unroll
        for (int rg = 0; rg < 4; ++rg)
#pragma unroll
            for (int r = 0; r < 4; ++r)
                atomicAdd(&Zrow[rowbase + rg * 16 + quad * 4 + r], zacc[rg][r]);
    }

    // ---- last-arrival finale (nobody spins) ----
    __threadfence();                               // release Z adds + diag stores
    __syncthreads();
    if (tid == 0) {
        unsigned my = __hip_atomic_fetch_add(&g_ctr, 1u, __ATOMIC_ACQ_REL,
                                             __HIP_MEMORY_SCOPE_AGENT);
        lastflag = ((my & 511u) == 511u);          // 512th arrival this replay
    }
    __syncthreads();
    if (lastflag) {
        __threadfence();                           // acquire others' writes
        float v = 0.f;
#pragma unroll
        for (int i = 0; i < 16; ++i) {             // 16 rows/thread, coalesced
            int row = i * 512 + tid;
            float Z = __hip_atomic_load(&Zrow[row], __ATOMIC_RELAXED,
                                        __HIP_MEMORY_SCOPE_AGENT);
            float dv = __hip_atomic_load(&diag[row], __ATOMIC_RELAXED,
                                         __HIP_MEMORY_SCOPE_AGENT);
            float p = __builtin_amdgcn_exp2f(dv) / Z;   // -KOFF cancels exactly
            v += -logf(p + 1e-5f);
        }
#pragma unroll
        for (int d = 1; d < 64; d <<= 1) v += __shfl_xor(v, d, 64);
        if (lane == 0) red[wave] = v;
        __syncthreads();
        if (tid == 0)
            out[0] = (((red[0] + red[1]) + (red[2] + red[3]))
                    + ((red[4] + red[5]) + (red[6] + red[7]))) * (1.f / 8192.f);
    }
}

extern "C" void kernel_launch(void* const* d_in, const int* in_sizes, int n_in,
                              void* d_out, int out_size, void* d_ws, size_t ws_size,
                              hipStream_t stream) {
    const float* q = (const float*)d_in[0];
    const float* g = (const float*)d_in[1];
    char* ws = (char*)d_ws;
    char*  qb   = ws;                                          // 2 MiB fp8 panels
    char*  gb   = ws + (2u << 20);                             // 2 MiB fp8 panels
    float* diag = (float*)(ws + (4u << 20));                   // 32 KiB
    float* Zrow = (float*)(ws + (4u << 20) + (32u << 10));     // 32 KiB
    k_cvt <<<2048, 256, 0, stream>>>(q, g, qb, gb, Zrow);
    k_main<<<512,  512, 0, stream>>>(qb, gb, Zrow, diag, (float*)d_out);
    (void)in_sizes; (void)n_in; (void)out_size; (void)ws_size;
}

// Round 7
// 150.463 us; speedup vs baseline: 1.9923x; 1.0529x over previous
//
#include <hip/hip_runtime.h>
#include <stdint.h>

// triplet_loss_cl: loss = mean_i(-log(softmax(q G^T)[i,i] + 1e-5)), N=8192, D=256.
// Flash-style, never materialize logits. q pre-scaled by log2(e); MFMA C-input
// initialized to -KOFF so logits exit MFMA already offset; epilogue is bare exp2.
// Offset cancels exactly in p = exp2(l_ii)/sum exp2(l).
//
// Round 13: round-12's fused tail burned ~85us in 512 serialized ACQ_REL
// agent-scope RMWs on one counter (compute ran full speed per PMC: MfmaUtil
// 6.6% of 98us = the whole MFMA budget). Fix: RELAXED fetch_add arrivals
// (pipelines at the TCC) + fence-based ordering (one __threadfence per block,
// C++ fence-fence sync through the atomic), and a 2-level counter tree
// (8 leaves x 64 on separate 128B lines, then master x 8) to cap the worst
// serialized chain at 72 ops. diag via relaxed agent atomic stores.
// 8 waves x 64 rows (BM=512, grid 512, 2 blocks/CU): LDS traffic 256MB, MFMA
// floor 7.4us. Spill guards: launch_bounds(512,2), cf loop not unrolled.
// A/B use the identical chunk packing, so any k-permutation in the HW fragment
// map applies to both operands and cancels in the dot product.

#define LOG2E 1.44269504f
#define KOFF  92.3324826f          // 64 * log2(e); cancels exactly in p = e_ii/Z

typedef __attribute__((ext_vector_type(4))) float f32x4;
typedef __attribute__((ext_vector_type(4))) int   i32x4;
typedef __attribute__((ext_vector_type(8))) int   i32x8;

typedef __attribute__((address_space(1))) const uint32_t gu32;
typedef __attribute__((address_space(3))) uint32_t lu32;

__device__ unsigned g_sub[8 * 32]; // 8 leaf counters, 128B apart; monotonic
__device__ unsigned g_master;      // monotonic; .bss zeroed at module load

static __device__ __forceinline__ i32x8 cat8(i32x4 lo, i32x4 hi) {
    i32x8 r;
    r[0] = lo[0]; r[1] = lo[1]; r[2] = lo[2]; r[3] = lo[3];
    r[4] = hi[0]; r[5] = hi[1]; r[6] = hi[2]; r[7] = hi[3];
    return r;
}

// ---- kernel 0: fp32 row-major [8192][256] -> fp8 e4m3 K=128 fragment layout ----
// Panel = 64 rows x 256 k = 16 KB, split into 8 tiles (kb in 2, cf in 4) of 2 KB.
// Tile holds rows cf*16+l15, k = kb*128 + quad*32 .. +32 per lane (l=quad*16+l15),
// stored as [h in 2][lane][16B] so fragment loads are linear b128 pairs.
// Thread o -> row = o>>5 (coalesced reads), slot = o&31 (8 k-values each).
// Blocks 0..31 also zero the Zrow accumulator (stream-ordered before k_main).
__global__ __launch_bounds__(256) void k_cvt(const float* __restrict__ q,
                                             const float* __restrict__ g,
                                             char* __restrict__ qb,
                                             char* __restrict__ gb,
                                             float* __restrict__ Zrow) {
    if (blockIdx.x < 32) Zrow[blockIdx.x * 256 + threadIdx.x] = 0.f;
    int o = blockIdx.x * 256 + threadIdx.x;        // grid 2048: q then g
    const float* src = q;
    char* dst = qb;
    float sc = LOG2E;
    if (o >= 262144) { o -= 262144; src = g; dst = gb; sc = 1.0f; }
    int row = o >> 5, slot = o & 31;
    const float4* sp = (const float4*)(src + row * 256 + slot * 8);
    float4 a = sp[0], b = sp[1];
    uint32_t w0 = __builtin_amdgcn_cvt_pk_fp8_f32(a.x * sc, a.y * sc, 0, false);
    w0 = __builtin_amdgcn_cvt_pk_fp8_f32(a.z * sc, a.w * sc, w0, true);
    uint32_t w1 = __builtin_amdgcn_cvt_pk_fp8_f32(b.x * sc, b.y * sc, 0, false);
    w1 = __builtin_amdgcn_cvt_pk_fp8_f32(b.z * sc, b.w * sc, w1, true);
    int p = row >> 6, cf = (row >> 4) & 3, l15 = row & 15;
    int kb = slot >> 4;                            // which 128-k block
    int gi = slot & 15;                            // 8-byte granule within block
    int quad = gi >> 2;                            // lane quad (k = quad*32..+32)
    int j = gi & 3;                                // byte granule within lane's 32B
    uint2 wv; wv.x = w0; wv.y = w1;
    *(uint2*)(dst + (size_t)p * 16384 + ((kb * 4 + cf) << 11)
              + ((j >> 1) << 10) + (quad * 16 + l15) * 16 + (j & 1) * 8) = wv;
}

// ---- kernel 1: per-row Z (atomic) + diagonal + last-block loss finale ----
// grid 512 = 16 row-tiles (BM=512) x 32 col-splits (256 cols). 8 waves x 64 rows.
// Double-buffered B tiles: per jt {stage jt+1 -> buf^1 | 4 cf x (4 ds_read_b128 +
// 16 MX-MFMA) on buf | one barrier}. Unit e8m0 scales (0x7F = 2^0) = exact fp8.
// Epilogue: atomicAdd Z partials into Zrow; last arrival through the relaxed
// counter tree (nobody spins) computes the final mean loss.
__global__ __launch_bounds__(512, 2) void k_main(const char* __restrict__ qb,
                                                 const char* __restrict__ gb,
                                                 float* __restrict__ Zrow,
                                                 float* __restrict__ diag,
                                                 float* __restrict__ out) {
    __shared__ char lds[2][16384];                 // double-buffered 64-col B tile
    __shared__ float red[8];
    __shared__ int lastflag;
    const int tid  = threadIdx.x;
    const int wave = tid >> 6;                     // 0..7
    const int lane = tid & 63;
    const int l15  = lane & 15;
    const int quad = lane >> 4;
    const int t    = blockIdx.x >> 5;              // row-tile (512 rows), 0..15
    const int cs   = blockIdx.x & 31;              // col-split (256 cols)
    const int p64  = t * 8 + wave;                 // global 64-row panel index
    const int rowbase = p64 * 64;

    // A fragments: wave owns q-panel p64; rowgroup rg = tile cf. 64 VGPRs.
    i32x8 afrag[4][2];
    {
        const char* qp = qb + (size_t)p64 * 16384 + lane * 16;
#pragma unroll
        for (int rg = 0; rg < 4; ++rg)
#pragma unroll
            for (int kb = 0; kb < 2; ++kb) {
                const char* tp = qp + ((kb * 4 + rg) << 11);
                afrag[rg][kb] = cat8(*(const i32x4*)tp, *(const i32x4*)(tp + 1024));
            }
    }

    float zacc[4][4];
#pragma unroll
    for (int rg = 0; rg < 4; ++rg)
#pragma unroll
        for (int r = 0; r < 4; ++r) zacc[rg][r] = 0.f;

    // stage(jt, buf): 16 KB DMA, 8 waves x 2 x 1KB (linear; dest = uniform+lane*16)
    const char* gbase = gb + (size_t)(cs * 4) * 16384;
#define STAGE(JT, BUF)                                                        \
    {                                                                         \
        const char* gp = gbase + (size_t)(JT) * 16384;                        \
        _Pragma("unroll")                                                     \
        for (int i = 0; i < 2; ++i) {                                         \
            int c = wave * 2 + i;                                             \
            __builtin_amdgcn_global_load_lds(                                 \
                (gu32*)(gp + (c << 10) + (lane << 4)),                        \
                (lu32*)(&lds[BUF][0] + (c << 10)), 16, 0, 0);                 \
        }                                                                     \
    }

    STAGE(0, 0);
    __syncthreads();                               // implicit vmcnt(0) drain
    int cur = 0;

    for (int jt = 0; jt < 4; ++jt) {
        if (jt < 3) STAGE(jt + 1, cur ^ 1);        // prefetch next tile

        const bool dg = (cs * 4 + jt == p64);      // tile holds our diagonal
        const char* lbase = &lds[cur][0] + lane * 16;
#pragma unroll 1                                   // runtime cf: caps B in flight
        for (int cf = 0; cf < 4; ++cf) {
            f32x4 acc[4];
#pragma unroll
            for (int rg = 0; rg < 4; ++rg)
                acc[rg] = (f32x4){-KOFF, -KOFF, -KOFF, -KOFF};
#pragma unroll
            for (int kb = 0; kb < 2; ++kb) {
                const char* bp = lbase + (cf << 11) + (kb << 13);
                i32x8 b = cat8(*(const i32x4*)bp, *(const i32x4*)(bp + 1024));
#pragma unroll
                for (int rg = 0; rg < 4; ++rg)
                    acc[rg] = __builtin_amdgcn_mfma_scale_f32_16x16x128_f8f6f4(
                        afrag[rg][kb], b, acc[rg],
                        0, 0,                       // cbsz/blgp: fp8 e4m3 / fp8 e4m3
                        0, 0x7f7f7f7f,              // scale A: e8m0 127 -> x1
                        0, 0x7f7f7f7f);             // scale B: e8m0 127 -> x1
            }
            // C/D layout: col=lane&15, row=quad*4+reg (shape-determined, m127/m128)
#pragma unroll
            for (int rg = 0; rg < 4; ++rg)
#pragma unroll
                for (int r = 0; r < 4; ++r)
                    zacc[rg][r] += __builtin_amdgcn_exp2f(acc[rg][r]);
            if (dg) {                              // diag: rg==cf, l15 == quad*4+r
#pragma unroll
                for (int rg = 0; rg < 4; ++rg)
                    if (rg == cf) {
#pragma unroll
                        for (int r = 0; r < 4; ++r)
                            if (quad * 4 + r == l15)
                                __hip_atomic_store(&diag[rowbase + cf * 16 + l15],
                                                   acc[rg][r], __ATOMIC_RELAXED,
                                                   __HIP_MEMORY_SCOPE_AGENT);
                    }
            }
        }
        if (jt < 3) {
            __syncthreads();                       // drains this iter's STAGE
            cur ^= 1;
        }
    }
#undef STAGE

    // fold the 16 column-lane-classes (lanes differing in bits 0..3 share a row)
#pragma unroll
    for (int d = 1; d < 16; d <<= 1)
#pragma unroll
        for (int rg = 0; rg < 4; ++rg)
#pragma unroll
            for (int r = 0; r < 4; ++r)
                zacc[rg][r] += __shfl_xor(zacc[rg][r], d, 64);

    if (l15 == 0) {                                // 32 adds/row total, low contention
#pragma unroll
        for (int rg = 0; rg < 4; ++rg)
#pragma unroll
            for (int r = 0; r < 4; ++r)
                atomicAdd(&Zrow[rowbase + rg * 16 + quad * 4 + r], zacc[rg][r]);
    }

    // ---- last-arrival finale: relaxed counter tree, fence-based sync ----
    __threadfence();                               // release Z adds + diag stores
    __syncthreads();
    if (tid == 0) {
        int s = (blockIdx.x & 7) * 32;             // leaf counters 128B apart
        unsigned my = __hip_atomic_fetch_add(&g_sub[s], 1u, __ATOMIC_RELAXED,
                                             __HIP_MEMORY_SCOPE_AGENT);
        int last = 0;
        if ((my & 63u) == 63u) {                   // last of this leaf's 64
            __threadfence();                       // acquire leaf / release onward
            unsigned mm = __hip_atomic_fetch_add(&g_master, 1u, __ATOMIC_RELAXED,
                                                 __HIP_MEMORY_SCOPE_AGENT);
            last = ((mm & 7u) == 7u);              // 8th leaf this replay
        }
        lastflag = last;
    }
    __syncthreads();
    if (lastflag) {
        __threadfence();                           // acquire all blocks' writes
        float v = 0.f;
#pragma unroll
        for (int i = 0; i < 16; ++i) {             // 16 rows/thread, coalesced
            int row = i * 512 + tid;
            float Z = __hip_atomic_load(&Zrow[row], __ATOMIC_RELAXED,
                                        __HIP_MEMORY_SCOPE_AGENT);
            float dv = __hip_atomic_load(&diag[row], __ATOMIC_RELAXED,
                                         __HIP_MEMORY_SCOPE_AGENT);
            float p = __builtin_amdgcn_exp2f(dv) / Z;   // -KOFF cancels exactly
            v += -logf(p + 1e-5f);
        }
#pragma unroll
        for (int d = 1; d < 64; d <<= 1) v += __shfl_xor(v, d, 64);
        if (lane == 0) red[wave] = v;
        __syncthreads();
        if (tid == 0)
            out[0] = (((red[0] + red[1]) + (red[2] + red[3]))
                    + ((red[4] + red[5]) + (red[6] + red[7]))) * (1.f / 8192.f);
    }
}

extern "C" void kernel_launch(void* const* d_in, const int* in_sizes, int n_in,
                              void* d_out, int out_size, void* d_ws, size_t ws_size,
                              hipStream_t stream) {
    const float* q = (const float*)d_in[0];
    const float* g = (const float*)d_in[1];
    char* ws = (char*)d_ws;
    char*  qb   = ws;                                          // 2 MiB fp8 panels
    char*  gb   = ws + (2u << 20);                             // 2 MiB fp8 panels
    float* diag = (float*)(ws + (4u << 20));                   // 32 KiB
    float* Zrow = (float*)(ws + (4u << 20) + (32u << 10));     // 32 KiB
    k_cvt <<<2048, 256, 0, stream>>>(q, g, qb, gb, Zrow);
    k_main<<<512,  512, 0, stream>>>(qb, gb, Zrow, diag, (float*)d_out);
    (void)in_sizes; (void)n_in; (void)out_size; (void)ws_size;
}

// Round 8
// 97.916 us; speedup vs baseline: 3.0615x; 1.5367x over previous
//
#include <hip/hip_runtime.h>
#include <stdint.h>

// triplet_loss_cl: loss = mean_i(-log(softmax(q G^T)[i,i] + 1e-5)), N=8192, D=256.
// Flash-style, never materialize logits. q pre-scaled by log2(e); MFMA C-input
// initialized to -KOFF so logits exit MFMA already offset; epilogue is bare exp2.
// Offset cancels exactly in p = exp2(l_ii)/sum exp2(l).
//
// Round 14: the ~85us fused-tail cost is the per-block __threadfence (agent
// release fence = L2 cache maintenance, ~160ns x 512 serialized chip-wide) --
// NOT the RMW mode (round 13: relaxed tree only bought 98->91us). Visibility
// never needed the fence: round-13 passed although a fence only flushes the
// issuing XCD -- i.e. Zrow atomicAdds / agent-scope diag stores / agent loads
// are coherence-point ops already. Ordering comes free from the vmcnt(0) ack
// drain at the tail barrier. So: FENCE-FREE tail. relaxed leaf fetch_add ->
// leaf-last relaxed master fetch_add (data-dependent) -> master-last finale
// with relaxed agent loads. Zero cache-maintenance instructions in the tail.
// 8 waves x 64 rows (BM=512, grid 512, 2 blocks/CU): LDS traffic 256MB, MFMA
// floor 7.4us. Spill guards: launch_bounds(512,2), cf loop not unrolled.
// A/B use the identical chunk packing, so any k-permutation in the HW fragment
// map applies to both operands and cancels in the dot product.

#define LOG2E 1.44269504f
#define KOFF  92.3324826f          // 64 * log2(e); cancels exactly in p = e_ii/Z

typedef __attribute__((ext_vector_type(4))) float f32x4;
typedef __attribute__((ext_vector_type(4))) int   i32x4;
typedef __attribute__((ext_vector_type(8))) int   i32x8;

typedef __attribute__((address_space(1))) const uint32_t gu32;
typedef __attribute__((address_space(3))) uint32_t lu32;

__device__ unsigned g_sub[8 * 32]; // 8 leaf counters, 128B apart; monotonic
__device__ unsigned g_master;      // monotonic; .bss zeroed at module load

static __device__ __forceinline__ i32x8 cat8(i32x4 lo, i32x4 hi) {
    i32x8 r;
    r[0] = lo[0]; r[1] = lo[1]; r[2] = lo[2]; r[3] = lo[3];
    r[4] = hi[0]; r[5] = hi[1]; r[6] = hi[2]; r[7] = hi[3];
    return r;
}

// ---- kernel 0: fp32 row-major [8192][256] -> fp8 e4m3 K=128 fragment layout ----
// Panel = 64 rows x 256 k = 16 KB, split into 8 tiles (kb in 2, cf in 4) of 2 KB.
// Tile holds rows cf*16+l15, k = kb*128 + quad*32 .. +32 per lane (l=quad*16+l15),
// stored as [h in 2][lane][16B] so fragment loads are linear b128 pairs.
// Thread o -> row = o>>5 (coalesced reads), slot = o&31 (8 k-values each).
// Blocks 0..31 also zero the Zrow accumulator (stream-ordered before k_main).
__global__ __launch_bounds__(256) void k_cvt(const float* __restrict__ q,
                                             const float* __restrict__ g,
                                             char* __restrict__ qb,
                                             char* __restrict__ gb,
                                             float* __restrict__ Zrow) {
    if (blockIdx.x < 32) Zrow[blockIdx.x * 256 + threadIdx.x] = 0.f;
    int o = blockIdx.x * 256 + threadIdx.x;        // grid 2048: q then g
    const float* src = q;
    char* dst = qb;
    float sc = LOG2E;
    if (o >= 262144) { o -= 262144; src = g; dst = gb; sc = 1.0f; }
    int row = o >> 5, slot = o & 31;
    const float4* sp = (const float4*)(src + row * 256 + slot * 8);
    float4 a = sp[0], b = sp[1];
    uint32_t w0 = __builtin_amdgcn_cvt_pk_fp8_f32(a.x * sc, a.y * sc, 0, false);
    w0 = __builtin_amdgcn_cvt_pk_fp8_f32(a.z * sc, a.w * sc, w0, true);
    uint32_t w1 = __builtin_amdgcn_cvt_pk_fp8_f32(b.x * sc, b.y * sc, 0, false);
    w1 = __builtin_amdgcn_cvt_pk_fp8_f32(b.z * sc, b.w * sc, w1, true);
    int p = row >> 6, cf = (row >> 4) & 3, l15 = row & 15;
    int kb = slot >> 4;                            // which 128-k block
    int gi = slot & 15;                            // 8-byte granule within block
    int quad = gi >> 2;                            // lane quad (k = quad*32..+32)
    int j = gi & 3;                                // byte granule within lane's 32B
    uint2 wv; wv.x = w0; wv.y = w1;
    *(uint2*)(dst + (size_t)p * 16384 + ((kb * 4 + cf) << 11)
              + ((j >> 1) << 10) + (quad * 16 + l15) * 16 + (j & 1) * 8) = wv;
}

// ---- kernel 1: per-row Z (atomic) + diagonal + last-block loss finale ----
// grid 512 = 16 row-tiles (BM=512) x 32 col-splits (256 cols). 8 waves x 64 rows.
// Double-buffered B tiles: per jt {stage jt+1 -> buf^1 | 4 cf x (4 ds_read_b128 +
// 16 MX-MFMA) on buf | one barrier}. Unit e8m0 scales (0x7F = 2^0) = exact fp8.
// Epilogue: atomicAdd Z partials into Zrow; last arrival through the relaxed,
// FENCE-FREE counter tree (nobody spins) computes the final mean loss.
__global__ __launch_bounds__(512, 2) void k_main(const char* __restrict__ qb,
                                                 const char* __restrict__ gb,
                                                 float* __restrict__ Zrow,
                                                 float* __restrict__ diag,
                                                 float* __restrict__ out) {
    __shared__ char lds[2][16384];                 // double-buffered 64-col B tile
    __shared__ float red[8];
    __shared__ int lastflag;
    const int tid  = threadIdx.x;
    const int wave = tid >> 6;                     // 0..7
    const int lane = tid & 63;
    const int l15  = lane & 15;
    const int quad = lane >> 4;
    const int t    = blockIdx.x >> 5;              // row-tile (512 rows), 0..15
    const int cs   = blockIdx.x & 31;              // col-split (256 cols)
    const int p64  = t * 8 + wave;                 // global 64-row panel index
    const int rowbase = p64 * 64;

    // A fragments: wave owns q-panel p64; rowgroup rg = tile cf. 64 VGPRs.
    i32x8 afrag[4][2];
    {
        const char* qp = qb + (size_t)p64 * 16384 + lane * 16;
#pragma unroll
        for (int rg = 0; rg < 4; ++rg)
#pragma unroll
            for (int kb = 0; kb < 2; ++kb) {
                const char* tp = qp + ((kb * 4 + rg) << 11);
                afrag[rg][kb] = cat8(*(const i32x4*)tp, *(const i32x4*)(tp + 1024));
            }
    }

    float zacc[4][4];
#pragma unroll
    for (int rg = 0; rg < 4; ++rg)
#pragma unroll
        for (int r = 0; r < 4; ++r) zacc[rg][r] = 0.f;

    // stage(jt, buf): 16 KB DMA, 8 waves x 2 x 1KB (linear; dest = uniform+lane*16)
    const char* gbase = gb + (size_t)(cs * 4) * 16384;
#define STAGE(JT, BUF)                                                        \
    {                                                                         \
        const char* gp = gbase + (size_t)(JT) * 16384;                        \
        _Pragma("unroll")                                                     \
        for (int i = 0; i < 2; ++i) {                                         \
            int c = wave * 2 + i;                                             \
            __builtin_amdgcn_global_load_lds(                                 \
                (gu32*)(gp + (c << 10) + (lane << 4)),                        \
                (lu32*)(&lds[BUF][0] + (c << 10)), 16, 0, 0);                 \
        }                                                                     \
    }

    STAGE(0, 0);
    __syncthreads();                               // implicit vmcnt(0) drain
    int cur = 0;

    for (int jt = 0; jt < 4; ++jt) {
        if (jt < 3) STAGE(jt + 1, cur ^ 1);        // prefetch next tile

        const bool dg = (cs * 4 + jt == p64);      // tile holds our diagonal
        const char* lbase = &lds[cur][0] + lane * 16;
#pragma unroll 1                                   // runtime cf: caps B in flight
        for (int cf = 0; cf < 4; ++cf) {
            f32x4 acc[4];
#pragma unroll
            for (int rg = 0; rg < 4; ++rg)
                acc[rg] = (f32x4){-KOFF, -KOFF, -KOFF, -KOFF};
#pragma unroll
            for (int kb = 0; kb < 2; ++kb) {
                const char* bp = lbase + (cf << 11) + (kb << 13);
                i32x8 b = cat8(*(const i32x4*)bp, *(const i32x4*)(bp + 1024));
#pragma unroll
                for (int rg = 0; rg < 4; ++rg)
                    acc[rg] = __builtin_amdgcn_mfma_scale_f32_16x16x128_f8f6f4(
                        afrag[rg][kb], b, acc[rg],
                        0, 0,                       // cbsz/blgp: fp8 e4m3 / fp8 e4m3
                        0, 0x7f7f7f7f,              // scale A: e8m0 127 -> x1
                        0, 0x7f7f7f7f);             // scale B: e8m0 127 -> x1
            }
            // C/D layout: col=lane&15, row=quad*4+reg (shape-determined, m127/m128)
#pragma unroll
            for (int rg = 0; rg < 4; ++rg)
#pragma unroll
                for (int r = 0; r < 4; ++r)
                    zacc[rg][r] += __builtin_amdgcn_exp2f(acc[rg][r]);
            if (dg) {                              // diag: rg==cf, l15 == quad*4+r
#pragma unroll
                for (int rg = 0; rg < 4; ++rg)
                    if (rg == cf) {
#pragma unroll
                        for (int r = 0; r < 4; ++r)
                            if (quad * 4 + r == l15)
                                __hip_atomic_store(&diag[rowbase + cf * 16 + l15],
                                                   acc[rg][r], __ATOMIC_RELAXED,
                                                   __HIP_MEMORY_SCOPE_AGENT);
                    }
            }
        }
        if (jt < 3) {
            __syncthreads();                       // drains this iter's STAGE
            cur ^= 1;
        }
    }
#undef STAGE

    // fold the 16 column-lane-classes (lanes differing in bits 0..3 share a row)
#pragma unroll
    for (int d = 1; d < 16; d <<= 1)
#pragma unroll
        for (int rg = 0; rg < 4; ++rg)
#pragma unroll
            for (int r = 0; r < 4; ++r)
                zacc[rg][r] += __shfl_xor(zacc[rg][r], d, 64);

    if (l15 == 0) {                                // 32 adds/row total, low contention
#pragma unroll
        for (int rg = 0; rg < 4; ++rg)
#pragma unroll
            for (int r = 0; r < 4; ++r)
                atomicAdd(&Zrow[rowbase + rg * 16 + quad * 4 + r], zacc[rg][r]);
    }

    // ---- last-arrival finale: relaxed counter tree, FENCE-FREE ----
    // Ordering = hardware completion: vmcnt(0) acks all this wave's coherence-
    // point ops (atomicAdds / agent stores) before the barrier; tid0's leaf RMW
    // issues only after every wave passed it. NO cache-maintenance instructions.
    asm volatile("s_waitcnt vmcnt(0)" ::: "memory");
    __syncthreads();
    if (tid == 0) {
        int s = (blockIdx.x & 7) * 32;             // leaf counters 128B apart
        unsigned my = __hip_atomic_fetch_add(&g_sub[s], 1u, __ATOMIC_RELAXED,
                                             __HIP_MEMORY_SCOPE_AGENT);
        int last = 0;
        if ((my & 63u) == 63u) {                   // last of this leaf's 64
            unsigned mm = __hip_atomic_fetch_add(&g_master, 1u, __ATOMIC_RELAXED,
                                                 __HIP_MEMORY_SCOPE_AGENT);
            last = ((mm & 7u) == 7u);              // 8th leaf this replay
        }
        lastflag = last;
    }
    __syncthreads();
    if (lastflag) {                                // all 512 blocks' data ack'd
        float v = 0.f;
#pragma unroll
        for (int i = 0; i < 16; ++i) {             // 16 rows/thread, coalesced
            int row = i * 512 + tid;
            float Z = __hip_atomic_load(&Zrow[row], __ATOMIC_RELAXED,
                                        __HIP_MEMORY_SCOPE_AGENT);
            float dv = __hip_atomic_load(&diag[row], __ATOMIC_RELAXED,
                                         __HIP_MEMORY_SCOPE_AGENT);
            float p = __builtin_amdgcn_exp2f(dv) / Z;   // -KOFF cancels exactly
            v += -logf(p + 1e-5f);
        }
#pragma unroll
        for (int d = 1; d < 64; d <<= 1) v += __shfl_xor(v, d, 64);
        if (lane == 0) red[wave] = v;
        __syncthreads();
        if (tid == 0)
            out[0] = (((red[0] + red[1]) + (red[2] + red[3]))
                    + ((red[4] + red[5]) + (red[6] + red[7]))) * (1.f / 8192.f);
    }
}

extern "C" void kernel_launch(void* const* d_in, const int* in_sizes, int n_in,
                              void* d_out, int out_size, void* d_ws, size_t ws_size,
                              hipStream_t stream) {
    const float* q = (const float*)d_in[0];
    const float* g = (const float*)d_in[1];
    char* ws = (char*)d_ws;
    char*  qb   = ws;                                          // 2 MiB fp8 panels
    char*  gb   = ws + (2u << 20);                             // 2 MiB fp8 panels
    float* diag = (float*)(ws + (4u << 20));                   // 32 KiB
    float* Zrow = (float*)(ws + (4u << 20) + (32u << 10));     // 32 KiB
    k_cvt <<<2048, 256, 0, stream>>>(q, g, qb, gb, Zrow);
    k_main<<<512,  512, 0, stream>>>(qb, gb, Zrow, diag, (float*)d_out);
    (void)in_sizes; (void)n_in; (void)out_size; (void)ws_size;
}

// Round 9
// 92.372 us; speedup vs baseline: 3.2452x; 1.0600x over previous
//
#include <hip/hip_runtime.h>
#include <stdint.h>

// triplet_loss_cl: loss = mean_i(-log(softmax(q G^T)[i,i] + 1e-5)), N=8192, D=256.
// Flash-style, never materialize logits. q pre-scaled by log2(e); MFMA C-input
// initialized to -KOFF so logits exit MFMA already offset; epilogue is bare exp2.
// Offset cancels exactly in p = exp2(l_ii)/sum exp2(l).
//
// Round 15: REVERT to the proven 3-dispatch round-10 structure (93.43us best).
// Rounds 11-14 mapped the cross-block-protocol cost curve: 512-arrival tails
// cost 20-230us (spin > acq_rel > fenced > fence-free) -- always more than the
// dispatch boundary they save; 32-arrival tails are ~free. So: keep cvt/main/fin
// as separate dispatches, and apply the (round-14-validated) FENCE-FREE tail
// only inside the 32-block k_fin: relaxed agent stores + s_waitcnt vmcnt(0) ack
// + relaxed monotonic __device__ counter (no zero-init, replay-safe), zero
// cache-maintenance instructions.
// k_main: 8 waves x 64 rows (BM=512, grid 512, 2 blocks/CU), MX-scaled fp8
// MFMA (unit e8m0 scales = exact fp8 math, 2x non-scaled rate), double-buffered
// 16KB B tiles, one barrier per jt. LDS traffic 256MB (~4.9us) < MFMA 7.4us.
// Spill guards: launch_bounds(512,2), cf loop not unrolled (<=2 B operands in
// flight), kb/rg static (no runtime-indexed arrays -> no scratch).
// A/B use the identical chunk packing, so any k-permutation in the HW fragment
// map applies to both operands and cancels in the dot product.

#define LOG2E 1.44269504f
#define KOFF  92.3324826f          // 64 * log2(e); cancels exactly in p = e_ii/Z

typedef __attribute__((ext_vector_type(4))) float f32x4;
typedef __attribute__((ext_vector_type(4))) int   i32x4;
typedef __attribute__((ext_vector_type(8))) int   i32x8;

typedef __attribute__((address_space(1))) const uint32_t gu32;
typedef __attribute__((address_space(3))) uint32_t lu32;

__device__ unsigned g_fin;         // .bss, zeroed at module load; monotonic

static __device__ __forceinline__ i32x8 cat8(i32x4 lo, i32x4 hi) {
    i32x8 r;
    r[0] = lo[0]; r[1] = lo[1]; r[2] = lo[2]; r[3] = lo[3];
    r[4] = hi[0]; r[5] = hi[1]; r[6] = hi[2]; r[7] = hi[3];
    return r;
}

// ---- kernel 0: fp32 row-major [8192][256] -> fp8 e4m3 K=128 fragment layout ----
// Panel = 64 rows x 256 k = 16 KB, split into 8 tiles (kb in 2, cf in 4) of 2 KB.
// Tile holds rows cf*16+l15, k = kb*128 + quad*32 .. +32 per lane (l=quad*16+l15),
// stored as [h in 2][lane][16B] so fragment loads are linear b128 pairs.
// Thread o -> row = o>>5 (coalesced reads), slot = o&31 (8 k-values each).
__global__ __launch_bounds__(256) void k_cvt(const float* __restrict__ q,
                                             const float* __restrict__ g,
                                             char* __restrict__ qb,
                                             char* __restrict__ gb) {
    int o = blockIdx.x * 256 + threadIdx.x;        // grid 2048: q then g
    const float* src = q;
    char* dst = qb;
    float sc = LOG2E;
    if (o >= 262144) { o -= 262144; src = g; dst = gb; sc = 1.0f; }
    int row = o >> 5, slot = o & 31;
    const float4* sp = (const float4*)(src + row * 256 + slot * 8);
    float4 a = sp[0], b = sp[1];
    uint32_t w0 = __builtin_amdgcn_cvt_pk_fp8_f32(a.x * sc, a.y * sc, 0, false);
    w0 = __builtin_amdgcn_cvt_pk_fp8_f32(a.z * sc, a.w * sc, w0, true);
    uint32_t w1 = __builtin_amdgcn_cvt_pk_fp8_f32(b.x * sc, b.y * sc, 0, false);
    w1 = __builtin_amdgcn_cvt_pk_fp8_f32(b.z * sc, b.w * sc, w1, true);
    int p = row >> 6, cf = (row >> 4) & 3, l15 = row & 15;
    int kb = slot >> 4;                            // which 128-k block
    int gi = slot & 15;                            // 8-byte granule within block
    int quad = gi >> 2;                            // lane quad (k = quad*32..+32)
    int j = gi & 3;                                // byte granule within lane's 32B
    uint2 wv; wv.x = w0; wv.y = w1;
    *(uint2*)(dst + (size_t)p * 16384 + ((kb * 4 + cf) << 11)
              + ((j >> 1) << 10) + (quad * 16 + l15) * 16 + (j & 1) * 8) = wv;
}

// ---- kernel 1: per-row Z partials (+ diagonal offset-logits) ----
// grid 512 = 16 row-tiles (BM=512) x 32 col-splits (256 cols). 8 waves x 64 rows.
// Double-buffered B tiles: per jt {stage jt+1 -> buf^1 | 4 cf x (4 ds_read_b128 +
// 16 MX-MFMA) on buf | one barrier}. Unit e8m0 scales (0x7F = 2^0) = exact fp8.
__global__ __launch_bounds__(512, 2) void k_main(const char* __restrict__ qb,
                                                 const char* __restrict__ gb,
                                                 float* __restrict__ zpart,
                                                 float* __restrict__ diag) {
    __shared__ char lds[2][16384];                 // double-buffered 64-col B tile
    const int tid  = threadIdx.x;
    const int wave = tid >> 6;                     // 0..7
    const int lane = tid & 63;
    const int l15  = lane & 15;
    const int quad = lane >> 4;
    const int t    = blockIdx.x >> 5;              // row-tile (512 rows), 0..15
    const int cs   = blockIdx.x & 31;              // col-split (256 cols)
    const int p64  = t * 8 + wave;                 // global 64-row panel index
    const int rowbase = p64 * 64;

    // A fragments: wave owns q-panel p64; rowgroup rg = tile cf. 64 VGPRs.
    i32x8 afrag[4][2];
    {
        const char* qp = qb + (size_t)p64 * 16384 + lane * 16;
#pragma unroll
        for (int rg = 0; rg < 4; ++rg)
#pragma unroll
            for (int kb = 0; kb < 2; ++kb) {
                const char* tp = qp + ((kb * 4 + rg) << 11);
                afrag[rg][kb] = cat8(*(const i32x4*)tp, *(const i32x4*)(tp + 1024));
            }
    }

    float zacc[4][4];
#pragma unroll
    for (int rg = 0; rg < 4; ++rg)
#pragma unroll
        for (int r = 0; r < 4; ++r) zacc[rg][r] = 0.f;

    // stage(jt, buf): 16 KB DMA, 8 waves x 2 x 1KB (linear; dest = uniform+lane*16)
    const char* gbase = gb + (size_t)(cs * 4) * 16384;
#define STAGE(JT, BUF)                                                        \
    {                                                                         \
        const char* gp = gbase + (size_t)(JT) * 16384;                        \
        _Pragma("unroll")                                                     \
        for (int i = 0; i < 2; ++i) {                                         \
            int c = wave * 2 + i;                                             \
            __builtin_amdgcn_global_load_lds(                                 \
                (gu32*)(gp + (c << 10) + (lane << 4)),                        \
                (lu32*)(&lds[BUF][0] + (c << 10)), 16, 0, 0);                 \
        }                                                                     \
    }

    STAGE(0, 0);
    __syncthreads();                               // implicit vmcnt(0) drain
    int cur = 0;

    for (int jt = 0; jt < 4; ++jt) {
        if (jt < 3) STAGE(jt + 1, cur ^ 1);        // prefetch next tile

        const bool dg = (cs * 4 + jt == p64);      // tile holds our diagonal
        const char* lbase = &lds[cur][0] + lane * 16;
#pragma unroll 1                                   // runtime cf: caps B in flight
        for (int cf = 0; cf < 4; ++cf) {
            f32x4 acc[4];
#pragma unroll
            for (int rg = 0; rg < 4; ++rg)
                acc[rg] = (f32x4){-KOFF, -KOFF, -KOFF, -KOFF};
#pragma unroll
            for (int kb = 0; kb < 2; ++kb) {
                const char* bp = lbase + (cf << 11) + (kb << 13);
                i32x8 b = cat8(*(const i32x4*)bp, *(const i32x4*)(bp + 1024));
#pragma unroll
                for (int rg = 0; rg < 4; ++rg)
                    acc[rg] = __builtin_amdgcn_mfma_scale_f32_16x16x128_f8f6f4(
                        afrag[rg][kb], b, acc[rg],
                        0, 0,                       // cbsz/blgp: fp8 e4m3 / fp8 e4m3
                        0, 0x7f7f7f7f,              // scale A: e8m0 127 -> x1
                        0, 0x7f7f7f7f);             // scale B: e8m0 127 -> x1
            }
            // C/D layout: col=lane&15, row=quad*4+reg (shape-determined, m127/m128)
#pragma unroll
            for (int rg = 0; rg < 4; ++rg)
#pragma unroll
                for (int r = 0; r < 4; ++r)
                    zacc[rg][r] += __builtin_amdgcn_exp2f(acc[rg][r]);
            if (dg) {                              // diag: rg==cf, l15 == quad*4+r
#pragma unroll
                for (int rg = 0; rg < 4; ++rg)
                    if (rg == cf) {
#pragma unroll
                        for (int r = 0; r < 4; ++r)
                            if (quad * 4 + r == l15)
                                diag[rowbase + cf * 16 + l15] = acc[rg][r];
                    }
            }
        }
        if (jt < 3) {
            __syncthreads();                       // drains this iter's STAGE
            cur ^= 1;
        }
    }
#undef STAGE

    // fold the 16 column-lane-classes (lanes differing in bits 0..3 share a row)
#pragma unroll
    for (int d = 1; d < 16; d <<= 1)
#pragma unroll
        for (int rg = 0; rg < 4; ++rg)
#pragma unroll
            for (int r = 0; r < 4; ++r)
                zacc[rg][r] += __shfl_xor(zacc[rg][r], d, 64);

    if (l15 == 0) {
#pragma unroll
        for (int rg = 0; rg < 4; ++rg)
#pragma unroll
            for (int r = 0; r < 4; ++r)
                zpart[(rowbase + rg * 16 + quad * 4 + r) * 32 + cs] = zacc[rg][r];
    }
}

// ---- kernel 2: per-row loss (32 blocks) + fence-free last-arrival finale ----
__global__ __launch_bounds__(256) void k_fin(const float* __restrict__ zpart,
                                             const float* __restrict__ diag,
                                             float* __restrict__ partial,
                                             float* __restrict__ out) {
    __shared__ float red[4];
    __shared__ int lastflag;
    int r = blockIdx.x * 256 + threadIdx.x;
    const float4* z = (const float4*)(zpart + r * 32);
    float Z = 0.f;
#pragma unroll
    for (int i = 0; i < 8; ++i) {
        float4 a = z[i];
        Z += (a.x + a.y) + (a.z + a.w);
    }
    float p = __builtin_amdgcn_exp2f(diag[r]) / Z;  // diag already has -KOFF folded
    float v = -logf(p + 1e-5f);
#pragma unroll
    for (int dd = 1; dd < 64; dd <<= 1) v += __shfl_xor(v, dd, 64);
    if ((threadIdx.x & 63) == 0) red[threadIdx.x >> 6] = v;
    __syncthreads();
    if (threadIdx.x == 0) {
        float bsum = (red[0] + red[1]) + (red[2] + red[3]);
        __hip_atomic_store(&partial[blockIdx.x], bsum,
                           __ATOMIC_RELAXED, __HIP_MEMORY_SCOPE_AGENT);
        // fence-free: vmcnt(0) acks the coherence-point store, then a relaxed
        // monotonic arrival RMW (validated round 14; no cache maintenance).
        asm volatile("s_waitcnt vmcnt(0)" ::: "memory");
        unsigned my = __hip_atomic_fetch_add(&g_fin, 1u, __ATOMIC_RELAXED,
                                             __HIP_MEMORY_SCOPE_AGENT);
        lastflag = ((my & 31u) == 31u);            // 32nd arrival this replay
    }
    __syncthreads();
    if (lastflag) {                                // we are the last block
        float v2 = 0.f;
        if (threadIdx.x < 32)
            v2 = __hip_atomic_load(&partial[threadIdx.x],
                                   __ATOMIC_RELAXED, __HIP_MEMORY_SCOPE_AGENT);
        if (threadIdx.x < 64) {
#pragma unroll
            for (int d = 1; d < 32; d <<= 1) v2 += __shfl_xor(v2, d, 64);
            if (threadIdx.x == 0) out[0] = v2 * (1.f / 8192.f);
        }
    }
}

extern "C" void kernel_launch(void* const* d_in, const int* in_sizes, int n_in,
                              void* d_out, int out_size, void* d_ws, size_t ws_size,
                              hipStream_t stream) {
    const float* q = (const float*)d_in[0];
    const float* g = (const float*)d_in[1];
    char* ws = (char*)d_ws;
    char*  qb     = ws;                                        // 2 MiB fp8 panels
    char*  gb     = ws + (2u << 20);                           // 2 MiB fp8 panels
    float* diag   = (float*)(ws + (4u << 20));                 // 32 KiB
    float* zpart  = (float*)(ws + (4u << 20) + (32u << 10));   // 1 MiB
    float* partial= (float*)(ws + (4u << 20) + (1056u << 10)); // 128 B
    k_cvt <<<2048, 256, 0, stream>>>(q, g, qb, gb);
    k_main<<<512,  512, 0, stream>>>(qb, gb, zpart, diag);
    k_fin <<<32,   256, 0, stream>>>(zpart, diag, partial, (float*)d_out);
    (void)in_sizes; (void)n_in; (void)out_size; (void)ws_size;
}

// Round 10
// 92.148 us; speedup vs baseline: 3.2531x; 1.0024x over previous
//
#include <hip/hip_runtime.h>
#include <stdint.h>

// triplet_loss_cl: loss = mean_i(-log(softmax(q G^T)[i,i] + 1e-5)), N=8192, D=256.
// Flash-style, never materialize logits. q pre-scaled by log2(e); MFMA C-input
// initialized to -KOFF so logits exit MFMA already offset; epilogue is bare exp2.
// Offset cancels exactly in p = exp2(l_ii)/sum exp2(l).
//
// Round 16: keep the proven 3-dispatch structure (92.37us). Single change:
// k_cvt store coalescing. Old cvt wrote scattered 8B granules into the fragment
// layout (partial-line writes -> 4.5us vs 3.3us BW floor). New cvt orders the
// output-granule index bits as (l15,quad,h,cf,kb,p) so store addr == o*16:
// 16B/lane fully coalesced stores, 64B/lane contiguous loads (4x float4, one
// row, 16 consecutive k). Output bytes are BIT-IDENTICAL to the old layout
// (granule holds k ascending: w0..w3), so k_main/k_fin are untouched.
// k_main: 8 waves x 64 rows (BM=512, grid 512, 2 blocks/CU), MX-scaled fp8
// MFMA (unit e8m0 scales = exact fp8 math, 2x non-scaled rate), double-buffered
// 16KB B tiles, one barrier per jt. k_fin: fence-free 32-arrival tail (r14/r15).
// A/B use the identical chunk packing, so any k-permutation in the HW fragment
// map applies to both operands and cancels in the dot product.

#define LOG2E 1.44269504f
#define KOFF  92.3324826f          // 64 * log2(e); cancels exactly in p = e_ii/Z

typedef __attribute__((ext_vector_type(4))) float f32x4;
typedef __attribute__((ext_vector_type(4))) int   i32x4;
typedef __attribute__((ext_vector_type(8))) int   i32x8;

typedef __attribute__((address_space(1))) const uint32_t gu32;
typedef __attribute__((address_space(3))) uint32_t lu32;

__device__ unsigned g_fin;         // .bss, zeroed at module load; monotonic

static __device__ __forceinline__ i32x8 cat8(i32x4 lo, i32x4 hi) {
    i32x8 r;
    r[0] = lo[0]; r[1] = lo[1]; r[2] = lo[2]; r[3] = lo[3];
    r[4] = hi[0]; r[5] = hi[1]; r[6] = hi[2]; r[7] = hi[3];
    return r;
}

// ---- kernel 0: fp32 row-major [8192][256] -> fp8 e4m3 K=128 fragment layout ----
// Panel = 64 rows x 256 k = 16 KB, split into 8 tiles (kb in 2, cf in 4) of 2 KB.
// 16B granule at (p,kb,cf,h,quad,l15) holds row cf*16+l15 (of panel p),
// k = kb*128 + quad*32 + h*16 .. +16, bytes in ascending k.
// Thread o = granule index ordered (l15,quad,h,cf,kb,p) LSB-first
//   -> store addr = o*16 (coalesced); load = 64B contiguous from one row.
__global__ __launch_bounds__(256) void k_cvt(const float* __restrict__ q,
                                             const float* __restrict__ g,
                                             char* __restrict__ qb,
                                             char* __restrict__ gb) {
    int o = blockIdx.x * 256 + threadIdx.x;        // grid 1024: q then g
    const float* src = q;
    char* dst = qb;
    float sc = LOG2E;
    if (o >= 131072) { o -= 131072; src = g; dst = gb; sc = 1.0f; }
    int l15  = o & 15;
    int quad = (o >> 4) & 3;
    int h    = (o >> 6) & 1;
    int cf   = (o >> 7) & 3;
    int kb   = (o >> 9) & 1;
    int p    = o >> 10;
    int row  = p * 64 + cf * 16 + l15;
    int k0   = kb * 128 + quad * 32 + h * 16;
    const float4* sp = (const float4*)(src + row * 256 + k0);
    float4 a = sp[0], b = sp[1], c = sp[2], d = sp[3];
    uint32_t w0 = __builtin_amdgcn_cvt_pk_fp8_f32(a.x * sc, a.y * sc, 0, false);
    w0 = __builtin_amdgcn_cvt_pk_fp8_f32(a.z * sc, a.w * sc, w0, true);
    uint32_t w1 = __builtin_amdgcn_cvt_pk_fp8_f32(b.x * sc, b.y * sc, 0, false);
    w1 = __builtin_amdgcn_cvt_pk_fp8_f32(b.z * sc, b.w * sc, w1, true);
    uint32_t w2 = __builtin_amdgcn_cvt_pk_fp8_f32(c.x * sc, c.y * sc, 0, false);
    w2 = __builtin_amdgcn_cvt_pk_fp8_f32(c.z * sc, c.w * sc, w2, true);
    uint32_t w3 = __builtin_amdgcn_cvt_pk_fp8_f32(d.x * sc, d.y * sc, 0, false);
    w3 = __builtin_amdgcn_cvt_pk_fp8_f32(d.z * sc, d.w * sc, w3, true);
    uint4 wv; wv.x = w0; wv.y = w1; wv.z = w2; wv.w = w3;
    *(uint4*)(dst + (size_t)o * 16) = wv;
}

// ---- kernel 1: per-row Z partials (+ diagonal offset-logits) ----
// grid 512 = 16 row-tiles (BM=512) x 32 col-splits (256 cols). 8 waves x 64 rows.
// Double-buffered B tiles: per jt {stage jt+1 -> buf^1 | 4 cf x (4 ds_read_b128 +
// 16 MX-MFMA) on buf | one barrier}. Unit e8m0 scales (0x7F = 2^0) = exact fp8.
__global__ __launch_bounds__(512, 2) void k_main(const char* __restrict__ qb,
                                                 const char* __restrict__ gb,
                                                 float* __restrict__ zpart,
                                                 float* __restrict__ diag) {
    __shared__ char lds[2][16384];                 // double-buffered 64-col B tile
    const int tid  = threadIdx.x;
    const int wave = tid >> 6;                     // 0..7
    const int lane = tid & 63;
    const int l15  = lane & 15;
    const int quad = lane >> 4;
    const int t    = blockIdx.x >> 5;              // row-tile (512 rows), 0..15
    const int cs   = blockIdx.x & 31;              // col-split (256 cols)
    const int p64  = t * 8 + wave;                 // global 64-row panel index
    const int rowbase = p64 * 64;

    // A fragments: wave owns q-panel p64; rowgroup rg = tile cf. 64 VGPRs.
    i32x8 afrag[4][2];
    {
        const char* qp = qb + (size_t)p64 * 16384 + lane * 16;
#pragma unroll
        for (int rg = 0; rg < 4; ++rg)
#pragma unroll
            for (int kb = 0; kb < 2; ++kb) {
                const char* tp = qp + ((kb * 4 + rg) << 11);
                afrag[rg][kb] = cat8(*(const i32x4*)tp, *(const i32x4*)(tp + 1024));
            }
    }

    float zacc[4][4];
#pragma unroll
    for (int rg = 0; rg < 4; ++rg)
#pragma unroll
        for (int r = 0; r < 4; ++r) zacc[rg][r] = 0.f;

    // stage(jt, buf): 16 KB DMA, 8 waves x 2 x 1KB (linear; dest = uniform+lane*16)
    const char* gbase = gb + (size_t)(cs * 4) * 16384;
#define STAGE(JT, BUF)                                                        \
    {                                                                         \
        const char* gp = gbase + (size_t)(JT) * 16384;                        \
        _Pragma("unroll")                                                     \
        for (int i = 0; i < 2; ++i) {                                         \
            int c = wave * 2 + i;                                             \
            __builtin_amdgcn_global_load_lds(                                 \
                (gu32*)(gp + (c << 10) + (lane << 4)),                        \
                (lu32*)(&lds[BUF][0] + (c << 10)), 16, 0, 0);                 \
        }                                                                     \
    }

    STAGE(0, 0);
    __syncthreads();                               // implicit vmcnt(0) drain
    int cur = 0;

    for (int jt = 0; jt < 4; ++jt) {
        if (jt < 3) STAGE(jt + 1, cur ^ 1);        // prefetch next tile

        const bool dg = (cs * 4 + jt == p64);      // tile holds our diagonal
        const char* lbase = &lds[cur][0] + lane * 16;
#pragma unroll 1                                   // runtime cf: caps B in flight
        for (int cf = 0; cf < 4; ++cf) {
            f32x4 acc[4];
#pragma unroll
            for (int rg = 0; rg < 4; ++rg)
                acc[rg] = (f32x4){-KOFF, -KOFF, -KOFF, -KOFF};
#pragma unroll
            for (int kb = 0; kb < 2; ++kb) {
                const char* bp = lbase + (cf << 11) + (kb << 13);
                i32x8 b = cat8(*(const i32x4*)bp, *(const i32x4*)(bp + 1024));
#pragma unroll
                for (int rg = 0; rg < 4; ++rg)
                    acc[rg] = __builtin_amdgcn_mfma_scale_f32_16x16x128_f8f6f4(
                        afrag[rg][kb], b, acc[rg],
                        0, 0,                       // cbsz/blgp: fp8 e4m3 / fp8 e4m3
                        0, 0x7f7f7f7f,              // scale A: e8m0 127 -> x1
                        0, 0x7f7f7f7f);             // scale B: e8m0 127 -> x1
            }
            // C/D layout: col=lane&15, row=quad*4+reg (shape-determined, m127/m128)
#pragma unroll
            for (int rg = 0; rg < 4; ++rg)
#pragma unroll
                for (int r = 0; r < 4; ++r)
                    zacc[rg][r] += __builtin_amdgcn_exp2f(acc[rg][r]);
            if (dg) {                              // diag: rg==cf, l15 == quad*4+r
#pragma unroll
                for (int rg = 0; rg < 4; ++rg)
                    if (rg == cf) {
#pragma unroll
                        for (int r = 0; r < 4; ++r)
                            if (quad * 4 + r == l15)
                                diag[rowbase + cf * 16 + l15] = acc[rg][r];
                    }
            }
        }
        if (jt < 3) {
            __syncthreads();                       // drains this iter's STAGE
            cur ^= 1;
        }
    }
#undef STAGE

    // fold the 16 column-lane-classes (lanes differing in bits 0..3 share a row)
#pragma unroll
    for (int d = 1; d < 16; d <<= 1)
#pragma unroll
        for (int rg = 0; rg < 4; ++rg)
#pragma unroll
            for (int r = 0; r < 4; ++r)
                zacc[rg][r] += __shfl_xor(zacc[rg][r], d, 64);

    if (l15 == 0) {
#pragma unroll
        for (int rg = 0; rg < 4; ++rg)
#pragma unroll
            for (int r = 0; r < 4; ++r)
                zpart[(rowbase + rg * 16 + quad * 4 + r) * 32 + cs] = zacc[rg][r];
    }
}

// ---- kernel 2: per-row loss (32 blocks) + fence-free last-arrival finale ----
__global__ __launch_bounds__(256) void k_fin(const float* __restrict__ zpart,
                                             const float* __restrict__ diag,
                                             float* __restrict__ partial,
                                             float* __restrict__ out) {
    __shared__ float red[4];
    __shared__ int lastflag;
    int r = blockIdx.x * 256 + threadIdx.x;
    const float4* z = (const float4*)(zpart + r * 32);
    float Z = 0.f;
#pragma unroll
    for (int i = 0; i < 8; ++i) {
        float4 a = z[i];
        Z += (a.x + a.y) + (a.z + a.w);
    }
    float p = __builtin_amdgcn_exp2f(diag[r]) / Z;  // diag already has -KOFF folded
    float v = -logf(p + 1e-5f);
#pragma unroll
    for (int dd = 1; dd < 64; dd <<= 1) v += __shfl_xor(v, dd, 64);
    if ((threadIdx.x & 63) == 0) red[threadIdx.x >> 6] = v;
    __syncthreads();
    if (threadIdx.x == 0) {
        float bsum = (red[0] + red[1]) + (red[2] + red[3]);
        __hip_atomic_store(&partial[blockIdx.x], bsum,
                           __ATOMIC_RELAXED, __HIP_MEMORY_SCOPE_AGENT);
        // fence-free: vmcnt(0) acks the coherence-point store, then a relaxed
        // monotonic arrival RMW (validated round 14; no cache maintenance).
        asm volatile("s_waitcnt vmcnt(0)" ::: "memory");
        unsigned my = __hip_atomic_fetch_add(&g_fin, 1u, __ATOMIC_RELAXED,
                                             __HIP_MEMORY_SCOPE_AGENT);
        lastflag = ((my & 31u) == 31u);            // 32nd arrival this replay
    }
    __syncthreads();
    if (lastflag) {                                // we are the last block
        float v2 = 0.f;
        if (threadIdx.x < 32)
            v2 = __hip_atomic_load(&partial[threadIdx.x],
                                   __ATOMIC_RELAXED, __HIP_MEMORY_SCOPE_AGENT);
        if (threadIdx.x < 64) {
#pragma unroll
            for (int d = 1; d < 32; d <<= 1) v2 += __shfl_xor(v2, d, 64);
            if (threadIdx.x == 0) out[0] = v2 * (1.f / 8192.f);
        }
    }
}

extern "C" void kernel_launch(void* const* d_in, const int* in_sizes, int n_in,
                              void* d_out, int out_size, void* d_ws, size_t ws_size,
                              hipStream_t stream) {
    const float* q = (const float*)d_in[0];
    const float* g = (const float*)d_in[1];
    char* ws = (char*)d_ws;
    char*  qb     = ws;                                        // 2 MiB fp8 panels
    char*  gb     = ws + (2u << 20);                           // 2 MiB fp8 panels
    float* diag   = (float*)(ws + (4u << 20));                 // 32 KiB
    float* zpart  = (float*)(ws + (4u << 20) + (32u << 10));   // 1 MiB
    float* partial= (float*)(ws + (4u << 20) + (1056u << 10)); // 128 B
    k_cvt <<<1024, 256, 0, stream>>>(q, g, qb, gb);
    k_main<<<512,  512, 0, stream>>>(qb, gb, zpart, diag);
    k_fin <<<32,   256, 0, stream>>>(zpart, diag, partial, (float*)d_out);
    (void)in_sizes; (void)n_in; (void)out_size; (void)ws_size;
}